// Round 3
// baseline (635.401 us; speedup 1.0000x reference)
//
#include <hip/hip_runtime.h>

// BlockLinearLayer: out[r, n*8+j] = sum_k x[r, n*32+k] * W[n,j,k] + b[n*8+j]
// x: [65536, 4096] f32, W: [128, 8, 32] f32, b: [1024] f32, out: [65536, 1024] f32
//
// Memory-bound: 1.342 GB total traffic, floor ~213 us at 6.29 TB/s copy ceiling.
// R2 (242 us) was phase-serialized per block (load -> barrier -> compute ->
// store) leaving the read pipe idle during compute/store. This version
// software-pipelines NT=16 row-tiles per block with double-buffered register
// prefetch (T14 async-stage): tile t+2's loads are issued during tile t's
// epilogue and consumed (ds_write) one full iteration later -> ~128 B/thread
// in flight across every barrier, read stream never drains.
// All global instrs remain full-line contiguous (reads 512 B runs, writes
// 128 B runs); LDS strides 132/36 dwords (=4 mod 32) -> min-phase conflict-free.

#define IN_COLS   4096
#define OUT_COLS  1024
#define NT        16        // row-tiles (of 64 rows) per block
#define XS        132       // ldsX row stride (dwords)
#define OS        36        // ldsO row stride (dwords)

__global__ __launch_bounds__(256, 3)
void blocklinear_kernel(const float* __restrict__ x,
                        const float* __restrict__ W,
                        const float* __restrict__ bias,
                        float* __restrict__ out)
{
    __shared__ float ldsX[64 * XS];    // 33792 B
    __shared__ float ldsO[64 * OS];    //  9216 B  (43008 total -> 3 blocks/CU)

    const int t     = threadIdx.x;
    const int chunk = blockIdx.x;                          // 0..31: 4 n-blocks
    const int w     = __builtin_amdgcn_readfirstlane(t >> 6);  // wave id 0..3
    const int l     = t & 63;                              // lane = row in tile
    const int n     = chunk * 4 + w;
    const float* Wn = W + (size_t)n * 256;

    const int f4  = t & 31;     // stage-in  float4-col (512 B row segment)
    const int rs  = t >> 5;     // stage-in  row-sub 0..7
    const int of4 = t & 7;      // stage-out float4-col (128 B row segment)
    const int ors = t >> 3;     // stage-out row-sub 0..31

    const int r0 = blockIdx.y * (NT * 64);
    const float* xin  = x + (size_t)(r0 + rs) * IN_COLS + chunk * 128 + f4 * 4;
    const size_t xtile = (size_t)64 * IN_COLS;

    float4 rA[8], rB[8];

    // ---- prologue: tile 0 -> rA; tile 1 -> rB (stays in flight); rA -> LDS
#pragma unroll
    for (int it = 0; it < 8; ++it)
        rA[it] = *reinterpret_cast<const float4*>(xin + (size_t)it * 8 * IN_COLS);
#pragma unroll
    for (int it = 0; it < 8; ++it)
        rB[it] = *reinterpret_cast<const float4*>(xin + xtile + (size_t)it * 8 * IN_COLS);
#pragma unroll
    for (int it = 0; it < 8; ++it)
        *reinterpret_cast<float4*>(&ldsX[(it * 8 + rs) * XS + f4 * 4]) = rA[it];
    __syncthreads();

#define BODY(TT, RNEXT, RPREF)                                                 \
    {                                                                          \
        float xv[32];                                                          \
        _Pragma("unroll")                                                      \
        for (int q = 0; q < 8; ++q) {                                          \
            float4 v = *reinterpret_cast<const float4*>(                       \
                &ldsX[l * XS + w * 32 + q * 4]);                               \
            xv[4*q+0] = v.x; xv[4*q+1] = v.y;                                  \
            xv[4*q+2] = v.z; xv[4*q+3] = v.w;                                  \
        }                                                                      \
        float acc[8];                                                          \
        _Pragma("unroll")                                                      \
        for (int j = 0; j < 8; ++j) {                                          \
            float s = bias[n * 8 + j];                                         \
            _Pragma("unroll")                                                  \
            for (int k = 0; k < 32; ++k)                                       \
                s = fmaf(Wn[j * 32 + k], xv[k], s);                            \
            acc[j] = s;                                                        \
        }                                                                      \
        reinterpret_cast<float4*>(&ldsO[l * OS + w * 8])[0] =                  \
            make_float4(acc[0], acc[1], acc[2], acc[3]);                       \
        reinterpret_cast<float4*>(&ldsO[l * OS + w * 8 + 4])[0] =              \
            make_float4(acc[4], acc[5], acc[6], acc[7]);                       \
        __syncthreads();  /* X reads done, O fully written */                  \
        _Pragma("unroll")                                                      \
        for (int m = 0; m < 2; ++m) {                                          \
            const int row = m * 32 + ors;                                      \
            float4 v = *reinterpret_cast<const float4*>(                       \
                &ldsO[row * OS + of4 * 4]);                                    \
            reinterpret_cast<float4*>(                                         \
                out + (size_t)(r0 + (TT) * 64 + row) * OUT_COLS                \
                    + chunk * 32)[of4] = v;                                    \
        }                                                                      \
        if ((TT) + 1 < NT) {                                                   \
            _Pragma("unroll")                                                  \
            for (int it = 0; it < 8; ++it)                                     \
                *reinterpret_cast<float4*>(                                    \
                    &ldsX[(it * 8 + rs) * XS + f4 * 4]) = RNEXT[it];           \
        }                                                                      \
        if ((TT) + 2 < NT) {                                                   \
            _Pragma("unroll")                                                  \
            for (int it = 0; it < 8; ++it)                                     \
                RPREF[it] = *reinterpret_cast<const float4*>(                  \
                    xin + ((size_t)(TT) + 2) * xtile                           \
                        + (size_t)it * 8 * IN_COLS);                           \
        }                                                                      \
        __syncthreads();  /* O reads done, X fully written */                  \
    }

    for (int tt = 0; tt < NT; tt += 2) {
        BODY(tt,     rB, rA)
        BODY(tt + 1, rA, rB)
    }
#undef BODY
}

extern "C" void kernel_launch(void* const* d_in, const int* in_sizes, int n_in,
                              void* d_out, int out_size, void* d_ws, size_t ws_size,
                              hipStream_t stream)
{
    const float* x = (const float*)d_in[0];
    const float* W = (const float*)d_in[1];
    const float* b = (const float*)d_in[2];
    float* out = (float*)d_out;

    const int rows = in_sizes[0] / IN_COLS;              // 65536
    dim3 grid(IN_COLS / 128, rows / (NT * 64));          // (32, 64)
    dim3 block(256);
    hipLaunchKernelGGL(blocklinear_kernel, grid, block, 0, stream, x, W, b, out);
}

// Round 4
// 275.681 us; speedup vs baseline: 2.3048x; 2.3048x over previous
//
#include <hip/hip_runtime.h>

// BlockLinearLayer: out[r, n*8+j] = sum_k x[r, n*32+k] * W[n,j,k] + b[n*8+j]
// x: [65536, 4096] f32, W: [128, 8, 32] f32, b: [1024] f32, out: [65536, 1024] f32
//
// Memory-bound: 1.342 GB traffic, floor ~213 us at the 6.29 TB/s copy ceiling.
// R2 (242 us): phase-serialized LDS-staged blocks, 4 blocks/CU. R3's explicit
// register pipeline regressed to 635 us: the compiler's vmcnt(0) drain before
// every s_barrier kills intra-block prefetch (guide Common-mistake #5).
// This version returns to the R2 structure but doubles cross-block phase
// interleave: 128-thread blocks (2 waves, 2 n-blocks, 17.4 KB LDS) at
// 8 blocks/CU -- overlap comes from independent blocks in staggered phases,
// which the barrier drain cannot defeat.
//   reads : 4 rows x 256 B contiguous runs per wave-instr
//   writes: 16 rows x 64 B full lines per wave-instr (via LDS transpose)
//   W/bias: wave-uniform index -> s_load broadcast (scalar cache)
// Nontemporal hints on x/out: pure streaming, no reuse.

#define IN_COLS   4096
#define OUT_COLS  1024
#define XS        68        // LDS x-row stride (dwords) = 64 + 4 pad
#define OS        20        // LDS out-row stride (dwords) = 16 + 4 pad

typedef float f32x4 __attribute__((ext_vector_type(4)));

__global__ __launch_bounds__(128, 4)
void blocklinear_kernel(const float* __restrict__ x,
                        const float* __restrict__ W,
                        const float* __restrict__ bias,
                        float* __restrict__ out)
{
    __shared__ float lds[64 * XS];     // 17408 B; out region overlays it
    const int t     = threadIdx.x;
    const int chunk = blockIdx.x;      // 0..63, each = 2 n-blocks (64 x-cols)
    const int r0    = blockIdx.y * 64;

    // ---- stage x tile [64 rows x 64 cols]: 8 iters, 4 rows x 256 B per instr
    {
        const int f4 = t & 15;         // float4 col 0..15 (256 B per row)
        const int rs = t >> 4;         // row-sub 0..7
        const float* xb = x + (size_t)(r0 + rs) * IN_COLS + chunk * 64 + f4 * 4;
#pragma unroll
        for (int it = 0; it < 8; ++it) {
            f32x4 v = __builtin_nontemporal_load(
                reinterpret_cast<const f32x4*>(xb + (size_t)it * 8 * IN_COLS));
            *reinterpret_cast<f32x4*>(&lds[(it * 8 + rs) * XS + f4 * 4]) = v;
        }
    }
    __syncthreads();

    // ---- compute: wave w owns n-block chunk*2+w, lane l owns row l
    const int w = __builtin_amdgcn_readfirstlane(t >> 6);   // 0..1, uniform
    const int l = t & 63;
    const int n = chunk * 2 + w;
    const float* Wn = W + (size_t)n * 256;

    float xv[32];
#pragma unroll
    for (int q = 0; q < 8; ++q) {
        f32x4 v = *reinterpret_cast<const f32x4*>(&lds[l * XS + w * 32 + q * 4]);
        xv[4*q+0] = v.x; xv[4*q+1] = v.y; xv[4*q+2] = v.z; xv[4*q+3] = v.w;
    }

    float acc[8];
#pragma unroll
    for (int j = 0; j < 8; ++j) {
        float s = bias[n * 8 + j];
#pragma unroll
        for (int k = 0; k < 32; ++k)
            s = fmaf(Wn[j * 32 + k], xv[k], s);
        acc[j] = s;
    }
    __syncthreads();   // all x reads done before overlaying LDS with out

    // ---- stage acc to LDS out region [64 rows x 16 cols]
    {
        f32x4 v0 = { acc[0], acc[1], acc[2], acc[3] };
        f32x4 v1 = { acc[4], acc[5], acc[6], acc[7] };
        reinterpret_cast<f32x4*>(&lds[l * OS + w * 8])[0] = v0;
        reinterpret_cast<f32x4*>(&lds[l * OS + w * 8 + 4])[0] = v1;
    }
    __syncthreads();

    // ---- cooperative store: 2 iters, 16 rows x 64 B full lines per instr
    {
        const int of4 = t & 3;         // float4 col 0..3 (64 B per row)
        const int ors = t >> 2;        // row-sub 0..31
#pragma unroll
        for (int m = 0; m < 2; ++m) {
            const int row = m * 32 + ors;
            f32x4 v = *reinterpret_cast<const f32x4*>(&lds[row * OS + of4 * 4]);
            __builtin_nontemporal_store(v, reinterpret_cast<f32x4*>(
                out + (size_t)(r0 + row) * OUT_COLS + chunk * 16 + of4 * 4));
        }
    }
}

extern "C" void kernel_launch(void* const* d_in, const int* in_sizes, int n_in,
                              void* d_out, int out_size, void* d_ws, size_t ws_size,
                              hipStream_t stream)
{
    const float* x = (const float*)d_in[0];
    const float* W = (const float*)d_in[1];
    const float* b = (const float*)d_in[2];
    float* out = (float*)d_out;

    const int rows = in_sizes[0] / IN_COLS;        // 65536
    dim3 grid(IN_COLS / 64, rows / 64);            // (64, 1024)
    dim3 block(128);
    hipLaunchKernelGGL(blocklinear_kernel, grid, block, 0, stream, x, W, b, out);
}